// Round 14
// baseline (106.767 us; speedup 1.0000x reference)
//
#include <hip/hip_runtime.h>

#define FEATS 768
#define NHEAD 12
#define HD    64
#define SEQ   1024
#define NB    8
#define MROWS (NB*SEQ)      // 8192
#define NQK   (2*FEATS)     // 1536
#define QKVN  (3*FEATS)     // 2304
#define QSC   0.0520616136f // (1/sqrt(768)) * log2(e), folded into Q at GEMM1 epilogue

typedef __attribute__((ext_vector_type(8))) __bf16          bf16x8;
typedef __attribute__((ext_vector_type(4))) __bf16          bf16x4;
typedef __attribute__((ext_vector_type(4))) unsigned short  us4;
typedef __attribute__((ext_vector_type(4))) float           f32x4;

__device__ __forceinline__ unsigned short f2bf(float f) {
  union { float f; unsigned u; } v; v.f = f;
  return (unsigned short)((v.u + 0x7fffu + ((v.u >> 16) & 1u)) >> 16);  // RNE
}

__device__ __forceinline__ void gload_lds16(const void* g, void* l) {
  __builtin_amdgcn_global_load_lds(
      (const __attribute__((address_space(1))) void*)g,
      (__attribute__((address_space(3))) void*)l, 16, 0, 0);
}

// ---------------- weight/bias casts (x-cast fused into gemm1) ----------------
__global__ void cast_all(const float* __restrict__ Wq, const float* __restrict__ Wk,
                         const float* __restrict__ Wv, const float* __restrict__ Wo,
                         const float* __restrict__ bq, const float* __restrict__ bk,
                         const float* __restrict__ bv,
                         unsigned short* __restrict__ Wcat,
                         unsigned short* __restrict__ Wobf,
                         float* __restrict__ bcat) {
  int blk = blockIdx.x;
  if (blk < 2304) {
    int mtx = blk / 576;
    int i = (blk % 576) * 256 + threadIdx.x;
    const float* src = (mtx == 0) ? Wq : (mtx == 1) ? Wk : (mtx == 2) ? Wv : Wo;
    f32x4 v = ((const f32x4*)src)[i];
    us4 o;
    o[0] = f2bf(v[0]); o[1] = f2bf(v[1]); o[2] = f2bf(v[2]); o[3] = f2bf(v[3]);
    if (mtx < 3) ((us4*)Wcat)[mtx * 147456 + i] = o;
    else         ((us4*)Wobf)[i] = o;
  } else {
    int i = (blk - 2304) * 256 + threadIdx.x;
    if (i < QKVN)
      bcat[i] = (i < FEATS) ? bq[i] : (i < 2*FEATS ? bk[i-FEATS] : bv[i-2*FEATS]);
  }
}

// read-side LDS swizzle (R7-R10 measured: 0 bank conflicts)
#define FOFF(row) ((row)*64 + (((g) ^ (((row) >> 1) & 3)) << 4))

// ---------------- GEMM1 v5: fused x-cast, A-write hoisted (2-deep A-reg dbuf) ------
// QKV = f2bf(x) * Wcat^T + bcat. ni 0..3 -> Q (pre-scaled by QSC), 4..7 -> K,
// 8..11 -> V^T (key columns PERMUTED per c(r) bit-perm -- see attn_kernel).
// vs R13 (net-neutral): WRITE_A moved from end-of-iter (serial tail: reg-wait +
// 32 f2bf + 2 ds_write + lgkm before barrier, +4.5us) to TOP of the NEXT iter,
// with A staged 2 ahead in regs (arE/arO): A(t+2) loaded at iter t, written at
// iter t+1 top -- regs land across a full iteration, ds_writes overlap MFMA.
// Safety: buf (t+1)&1 was last read during compute(t-1), before barrier(t-1);
// writing after that barrier is the standard dbuf window. Ledger (verified):
//   prologue: arE<-A(0), arO<-A(1), B(0), B(1); WRITE_A(arE,0) [waits arE];
//             vmcnt(3) [B(0) landed, B(1) rides]; lgkm(0); barrier.
//   even t:   WRITE_A(arO,1)=A(t+1); load arE<-A(t+2), B(t+2); compute(t);
//             vmcnt(7) [drains B(t+1); A(t+2)+B(t+2) ride]; lgkm(0); barrier.
//   odd  u:   WRITE_A(arE,0)=A(u+1); load arO<-A(u+2), B(u+2); compute(u);
//             vmcnt(7); lgkm(0); barrier.  Tail t=22: vmcnt(0) drains B(23).
__global__ __launch_bounds__(256, 3) void gemm1_bt(
    const float* __restrict__ X,
    const unsigned short* __restrict__ B,
    const float* __restrict__ bias,
    unsigned short* __restrict__ QKo,
    unsigned short* __restrict__ VTo)
{
  __shared__ __align__(16) char Al[2 * 8192];    // [buf][128 rows][64B] bf16
  __shared__ __align__(16) char Bl[3 * 12288];   // [buf][192 rows][64B]

  const int tid  = threadIdx.x;
  const int lane = tid & 63;
  const int w    = tid >> 6;
  const int l15  = lane & 15;
  const int g    = lane >> 4;
  const int wm   = (w >> 1) * 64;
  const int wn   = (w & 1) * 96;

  const int id  = blockIdx.x;            // 768 = 8 xcd * (8 mi * 12 ni)
  const int xcd = id & 7;
  const int j   = id >> 3;
  const int mi  = xcd * 8 + (j & 7);
  const int ni  = j >> 3;                // 0..11
  const int mbase = mi * 128;
  const int nbase = ni * 192;

  const int trow  = tid >> 2;
  const int sslot = ((tid & 3) ^ ((tid >> 3) & 3)) * 8;
  const float*          Ag = X + (size_t)(mbase + trow) * 768 + sslot;
  const unsigned short* Bg = B + (size_t)(nbase + trow) * 768 + sslot;

  f32x4 arE[4], arO[4];   // 2-deep A-register double buffer (named: rule #20)

  auto LOAD_A = [&](f32x4 (&ar)[4], int t) {
    const float* sa = Ag + t * 32;
    ar[0] = *(const f32x4*)(sa);
    ar[1] = *(const f32x4*)(sa + 4);
    ar[2] = *(const f32x4*)(sa + 64*768);
    ar[3] = *(const f32x4*)(sa + 64*768 + 4);
  };
  auto WRITE_A = [&](f32x4 (&ar)[4], int buf) {
    char* da = Al + buf * 8192 + tid * 16;
    us4 o0, o1;
#pragma unroll
    for (int k = 0; k < 4; k++) { o0[k] = f2bf(ar[0][k]); }
#pragma unroll
    for (int k = 0; k < 4; k++) { o1[k] = f2bf(ar[1][k]); }
    *(us4*)(da)     = o0;
    *(us4*)(da + 8) = o1;
#pragma unroll
    for (int k = 0; k < 4; k++) { o0[k] = f2bf(ar[2][k]); }
#pragma unroll
    for (int k = 0; k < 4; k++) { o1[k] = f2bf(ar[3][k]); }
    *(us4*)(da + 4096)     = o0;
    *(us4*)(da + 4096 + 8) = o1;
  };
  auto STAGE_B = [&](int buf, int t) {
    const unsigned short* sb = Bg + t * 32;
    char* db = Bl + buf * 12288 + tid * 16;
    gload_lds16(sb,            db);
    gload_lds16(sb + 64*768,   db + 4096);
    gload_lds16(sb + 128*768,  db + 8192);
  };

  f32x4 acc[4][6] = {};

  auto COMPUTE = [&](int t) {
    const char* Ab = Al + (t & 1) * 8192;
    const char* Bb = Bl + (t % 3) * 12288;
    bf16x8 af[4];
#pragma unroll
    for (int mf = 0; mf < 4; mf++) {
      const int row = wm + mf*16 + l15;
      af[mf] = *(const bf16x8*)(Ab + FOFF(row));
    }
    __builtin_amdgcn_s_setprio(1);
#pragma unroll
    for (int nf = 0; nf < 6; nf++) {
      const int row = wn + nf*16 + l15;
      bf16x8 bfv = *(const bf16x8*)(Bb + FOFF(row));
#pragma unroll
      for (int mf = 0; mf < 4; mf++)
        acc[mf][nf] = __builtin_amdgcn_mfma_f32_16x16x32_bf16(af[mf], bfv, acc[mf][nf], 0, 0, 0);
    }
    __builtin_amdgcn_s_setprio(0);
  };

  // prologue
  LOAD_A(arE, 0);
  LOAD_A(arO, 1);
  STAGE_B(0, 0);
  STAGE_B(1, 1);
  WRITE_A(arE, 0);                                   // waits arE; arO+B ride
  asm volatile("s_waitcnt vmcnt(3)" ::: "memory");   // B(0) landed; B(1) rides
  asm volatile("s_waitcnt lgkmcnt(0)" ::: "memory");
  __builtin_amdgcn_s_barrier();

#pragma unroll 1
  for (int t = 0; t < 24; t += 2) {
    // ---- even t: write A(t+1) (from arO) into buf1; prefetch A(t+2)->arE ----
    WRITE_A(arO, 1);                                 // t+1 <= 23 always
    if (t < 22) { LOAD_A(arE, t + 2); STAGE_B((t + 2) % 3, t + 2); }
    COMPUTE(t);
    if (t < 22) asm volatile("s_waitcnt vmcnt(7)" ::: "memory");
    else        asm volatile("s_waitcnt vmcnt(0)" ::: "memory");   // t=22: drain B(23)
    asm volatile("s_waitcnt lgkmcnt(0)" ::: "memory");
    __builtin_amdgcn_s_barrier();

    // ---- odd u = t+1: write A(u+1) (from arE) into buf0; prefetch A(u+2)->arO ----
    const int u = t + 1;
    if (u < 23) WRITE_A(arE, 0);
    if (u < 22) { LOAD_A(arO, u + 2); STAGE_B((u + 2) % 3, u + 2); }
    COMPUTE(u);
    if (u < 22) asm volatile("s_waitcnt vmcnt(7)" ::: "memory");
    if (u < 23) {
      asm volatile("s_waitcnt lgkmcnt(0)" ::: "memory");
      __builtin_amdgcn_s_barrier();
    }
  }

  // epilogue: D layout col = lane&15, row = (lane>>4)*4 + reg (m89-verified)
  const bool isQK = (ni < 8);            // block-uniform
  const float osc = (ni < 4) ? QSC : 1.0f;   // Q pre-scale (block-uniform)
#pragma unroll
  for (int mf = 0; mf < 4; mf++)
#pragma unroll
    for (int nf = 0; nf < 6; nf++) {
      const int col  = nbase + wn + nf*16 + l15;
      const float bb = bias[col];
      const int row0 = mbase + wm + mf*16 + g*4;
      if (isQK) {
#pragma unroll
        for (int r = 0; r < 4; r++)
          QKo[(size_t)(row0 + r)*NQK + col] = f2bf((acc[mf][nf][r] + bb) * osc);
      } else {
        const int c  = col - NQK;
        const int hh = c >> 6, dd = c & 63;
        const int bI = row0 >> 10, n0 = row0 & 1023;
        // key-column bit-permutation within the 64-key tile:
        // r = [b5b4 | b3b2 | b1b0] -> c = [b5 | b3b2 | b4 | b1b0]  (rr bits are 0)
        const int rl  = n0 & 63;
        const int cp  = ((rl >> 5) << 5) | (((rl >> 2) & 3) << 3) | (((rl >> 4) & 1) << 2);
        const int n0p = (n0 & ~63) | cp;
        us4 o;
#pragma unroll
        for (int r = 0; r < 4; r++) o[r] = f2bf(acc[mf][nf][r] + bb);
        *(us4*)(VTo + ((size_t)((bI*NHEAD + hh)*HD + dd))*SEQ + n0p) = o;
      }
    }
}

// ---------------- GEMM2: 64x128 tile, 768 blocks, asym A2/B3 counted-vmcnt ---------
// (R5-verified. FROZEN.)
__global__ __launch_bounds__(256, 4) void gemm2_bt(
    const unsigned short* __restrict__ A,
    const unsigned short* __restrict__ B,
    const float* __restrict__ bias,
    float* __restrict__ C)
{
  __shared__ __align__(16) char Al[2 * 4096];
  __shared__ __align__(16) char Bl[3 * 8192];

  const int tid  = threadIdx.x;
  const int lane = tid & 63;
  const int w    = tid >> 6;
  const int l15  = lane & 15;
  const int g    = lane >> 4;
  const int wm   = (w >> 1) * 32;
  const int wn   = (w & 1) * 64;

  const int id  = blockIdx.x;
  const int xcd = id & 7;
  const int j   = id >> 3;
  const int mi  = xcd * 16 + (j & 15);
  const int ni  = j >> 4;
  const int mbase = mi * 64;
  const int nbase = ni * 128;

  const int trow  = tid >> 2;
  const int sslot = ((tid & 3) ^ ((tid >> 3) & 3)) * 8;
  const unsigned short* Ag = A + (size_t)(mbase + trow) * 768 + sslot;
  const unsigned short* Bg = B + (size_t)(nbase + trow) * 768 + sslot;

  auto STAGE_A = [&](int buf, int t) {
    char* da = Al + buf * 4096 + tid * 16;
    gload_lds16(Ag + t * 32, da);
  };
  auto STAGE_B = [&](int buf, int t) {
    const unsigned short* sb = Bg + t * 32;
    char* db = Bl + buf * 8192 + tid * 16;
    gload_lds16(sb,           db);
    gload_lds16(sb + 64*768,  db + 4096);
  };

  f32x4 acc[2][4] = {};

  STAGE_A(0, 0);
  STAGE_B(0, 0);
  STAGE_B(1, 1);
  asm volatile("s_waitcnt vmcnt(2)" ::: "memory");   // A(0)+B(0) landed; B(1) in flight
  __builtin_amdgcn_s_barrier();

  for (int t = 0; t < 24; t++) {
    if (t < 23) STAGE_A((t + 1) & 1, t + 1);
    if (t < 22) STAGE_B((t + 2) % 3, t + 2);

    const char* Ab = Al + (t & 1) * 4096;
    const char* Bb = Bl + (t % 3) * 8192;
    bf16x8 af[2], bfv[4];
#pragma unroll
    for (int mf = 0; mf < 2; mf++) {
      const int row = wm + mf*16 + l15;
      af[mf] = *(const bf16x8*)(Ab + FOFF(row));
    }
#pragma unroll
    for (int nf = 0; nf < 4; nf++) {
      const int row = wn + nf*16 + l15;
      bfv[nf] = *(const bf16x8*)(Bb + FOFF(row));
    }
    __builtin_amdgcn_s_setprio(1);
#pragma unroll
    for (int mf = 0; mf < 2; mf++)
#pragma unroll
      for (int nf = 0; nf < 4; nf++)
        acc[mf][nf] = __builtin_amdgcn_mfma_f32_16x16x32_bf16(af[mf], bfv[nf], acc[mf][nf], 0, 0, 0);
    __builtin_amdgcn_s_setprio(0);

    if (t < 23) {
      if (t < 22) asm volatile("s_waitcnt vmcnt(2)" ::: "memory");
      else        asm volatile("s_waitcnt vmcnt(0)" ::: "memory");
      __builtin_amdgcn_s_barrier();
    }
  }

#pragma unroll
  for (int mf = 0; mf < 2; mf++)
#pragma unroll
    for (int nf = 0; nf < 4; nf++) {
      const int col  = nbase + wn + nf*16 + l15;
      const float bb = bias[col];
      const int row0 = mbase + wm + mf*16 + g*4;
#pragma unroll
      for (int r = 0; r < 4; r++)
        C[(size_t)(row0 + r)*FEATS + col] = acc[mf][nf][r] + bb;
    }
}
#undef FOFF

// ---------------- fused sigmoid attention v8 (R5-verified. FROZEN.) ----------------
// Pipeline QK(t) || sigmoid+PV(t-1); V staged one tile behind K; permuted-V
// in-register S (zero cross-lane: V^T key columns pre-permuted at GEMM1).
__global__ __launch_bounds__(256, 3) void attn_kernel(
    const unsigned short* __restrict__ QK,    // [8192][1536] (Q cols pre-scaled)
    const unsigned short* __restrict__ VT,    // [(b*12+h)*64 + d][1024], key-permuted
    const float* __restrict__ biasp,
    unsigned short* __restrict__ AO)          // [8192][768] bf16
{
  __shared__ __align__(16) char Kl[2][8192];   // [64 key][64 hd] bf16, XOR-swizzled
  __shared__ __align__(16) char Vl[2][8192];   // [64 d][64 keycol] bf16, XOR-swizzled

  const int tid  = threadIdx.x;
  const int lane = tid & 63;
  const int w    = tid >> 6;       // 0..3
  const int l15  = lane & 15;
  const int g    = lane >> 4;

  const int id  = blockIdx.x;
  const int r8  = id & 7;
  const int m   = id >> 3;
  const int bh  = r8 * 12 + (m >> 3);
  const int qx  = m & 7;
  const int b   = bh / NHEAD;
  const int h   = bh % NHEAD;
  const int rowB  = b * SEQ;
  const int qbase = rowB + qx * 128;

  const float Kb = __builtin_amdgcn_exp2f(-biasp[0] * 1.4426950408889634f);

  // Q fragments: qf[qm][ks], wave w rows [qbase+w*32+qm*16, +16)
  bf16x8 qf[2][2];
  {
    const unsigned short* qp = QK + (size_t)(qbase + w*32 + l15) * NQK + h*HD + g*8;
    qf[0][0] = *(const bf16x8*)(qp);
    qf[0][1] = *(const bf16x8*)(qp + 32);
    qf[1][0] = *(const bf16x8*)(qp + 16*NQK);
    qf[1][1] = *(const bf16x8*)(qp + 16*NQK + 32);
  }

  // staging: 256 thr x 16B = 4KB/issue; 2 issues per K tile (rows 0-31, 32-63), 2 per V
  const int trow = tid >> 3;                               // 0..31
  const int colb = ((tid & 7) * 16) ^ ((trow & 7) << 4);   // pre-swizzled source
  const char* Ksrc = (const char*)QK +
      ((size_t)(rowB + trow) * NQK + FEATS + h*HD) * 2 + colb;
  const char* Vsrc = (const char*)VT +
      ((size_t)(bh*HD + trow)) * (SEQ*2) + colb;

  auto STAGE_K = [&](int p, int t) {
    char* kw = Kl[p] + tid*16;
    gload_lds16(Ksrc + (size_t)t * 64 * (NQK*2),              kw);
    gload_lds16(Ksrc + (size_t)t * 64 * (NQK*2) + 32*(NQK*2), kw + 4096);
  };
  auto STAGE_V = [&](int p, int t) {
    char* vw = Vl[p] + tid*16;
    gload_lds16(Vsrc + t * 128,              vw);
    gload_lds16(Vsrc + t * 128 + 32*(SEQ*2), vw + 4096);
  };

  f32x4 o_acc[4][2] = {};
  f32x4 sE[2][4], sO[2][4];    // ping-pong score tiles (even/odd t)

  // sigmoid(prev scores) -> in-register bf16 B-frags (no cross-lane; V pre-permuted)
  auto SIGPV = [&](f32x4 (&sP)[2][4], const char* Vp) {
    bf16x8 paq[2][2];
#pragma unroll
    for (int qm = 0; qm < 2; qm++) {
      float sg[4][4];
#pragma unroll
      for (int nf = 0; nf < 4; nf++)
#pragma unroll
        for (int rr = 0; rr < 4; rr++) {
          const float e = __builtin_amdgcn_exp2f(-sP[qm][nf][rr]);
          sg[nf][rr] = __builtin_amdgcn_rcpf(__builtin_fmaf(Kb, e, 1.0f));
        }
#pragma unroll
      for (int js = 0; js < 2; js++) {
        bf16x8 pa;
#pragma unroll
        for (int jj = 0; jj < 4; jj++) {
          pa[jj]     = (__bf16)sg[2*js][jj];
          pa[jj + 4] = (__bf16)sg[2*js + 1][jj];
        }
        paq[qm][js] = pa;
      }
    }
#pragma unroll
    for (int js = 0; js < 2; js++) {
      bf16x8 vf[4];
#pragma unroll
      for (int df = 0; df < 4; df++) {
        const int row = df*16 + l15;
        const int by  = (row*128 + js*64 + g*16) ^ ((row & 7) << 4);
        vf[df] = *(const bf16x8*)(Vp + by);
      }
      __builtin_amdgcn_s_setprio(1);
#pragma unroll
      for (int df = 0; df < 4; df++)
#pragma unroll
        for (int qm = 0; qm < 2; qm++)
          o_acc[df][qm] = __builtin_amdgcn_mfma_f32_16x16x32_bf16(vf[df], paq[qm][js], o_acc[df][qm], 0, 0, 0);
      __builtin_amdgcn_s_setprio(0);
    }
  };

  // one pipeline stage: stage K(t+1),V(t); QK(t)->sC; sigmoid+PV of tile t-1; barrier
  auto BODY = [&](int t, f32x4 (&sC)[2][4], f32x4 (&sP)[2][4], bool stK, bool doPrev) {
    if (stK) STAGE_K((t + 1) & 1, t + 1);
    STAGE_V(t & 1, t);

    const char* Kp = Kl[t & 1];
#pragma unroll
    for (int qm = 0; qm < 2; qm++)
#pragma unroll
      for (int nf = 0; nf < 4; nf++)
        sC[qm][nf] = (f32x4){0.f, 0.f, 0.f, 0.f};
    __builtin_amdgcn_s_setprio(1);
#pragma unroll
    for (int nf = 0; nf < 4; nf++)
#pragma unroll
      for (int ks = 0; ks < 2; ks++) {
        const int row = nf*16 + l15;
        const int by  = (row*128 + ks*64 + g*16) ^ ((row & 7) << 4);
        bf16x8 kf = *(const bf16x8*)(Kp + by);
        sC[0][nf] = __builtin_amdgcn_mfma_f32_16x16x32_bf16(kf, qf[0][ks], sC[0][nf], 0, 0, 0);
        sC[1][nf] = __builtin_amdgcn_mfma_f32_16x16x32_bf16(kf, qf[1][ks], sC[1][nf], 0, 0, 0);
      }
    __builtin_amdgcn_s_setprio(0);

    if (doPrev) SIGPV(sP, Vl[(t - 1) & 1]);

    __syncthreads();
  };

  STAGE_K(0, 0);
  __syncthreads();

  BODY(0, sE, sO, true, false);          // QK(0); stage K(1),V(0)
#pragma unroll 1
  for (int t = 1; t < 15; t += 2) {
    BODY(t,     sO, sE, true, true);     // QK(t)  || sigmoid+PV(t-1)
    BODY(t + 1, sE, sO, true, true);
  }
  BODY(15, sO, sE, false, true);         // QK(15) || sigmoid+PV(14); stage V(15)
  SIGPV(sO, Vl[1]);                      // drain: sigmoid+PV(15)

  // ---- epilogue: o_acc[df][qm]: col=l15 -> q, row=df*16+g*4+rr -> d ----
  unsigned short* aop = AO + (size_t)(qbase + w*32) * FEATS + h*HD;
#pragma unroll
  for (int df = 0; df < 4; df++)
#pragma unroll
    for (int qm = 0; qm < 2; qm++) {
      const int q  = qm*16 + l15;
      const int d0 = df*16 + g*4;
      bf16x4 o;
#pragma unroll
      for (int rr = 0; rr < 4; rr++) o[rr] = (__bf16)o_acc[df][qm][rr];
      *(bf16x4*)(aop + (size_t)q * FEATS + d0) = o;
    }
}

// ---------------- launch ----------------
extern "C" void kernel_launch(void* const* d_in, const int* in_sizes, int n_in,
                              void* d_out, int out_size, void* d_ws, size_t ws_size,
                              hipStream_t stream) {
  const float* x    = (const float*)d_in[0];
  const float* bias = (const float*)d_in[1];
  const float* Wq   = (const float*)d_in[2];
  const float* bq   = (const float*)d_in[3];
  const float* Wk   = (const float*)d_in[4];
  const float* bk   = (const float*)d_in[5];
  const float* Wv   = (const float*)d_in[6];
  const float* bv   = (const float*)d_in[7];
  const float* Wo   = (const float*)d_in[8];
  const float* bo   = (const float*)d_in[9];
  float* out = (float*)d_out;

  char* ws = (char*)d_ws;
  unsigned short* Xbf  = (unsigned short*)(ws + 0);   // region reused as AO only
  unsigned short* Wcat = (unsigned short*)(ws + 12582912);
  unsigned short* Wobf = (unsigned short*)(ws + 16121856);
  float*          bcat = (float*)        (ws + 17301504);
  unsigned short* QKb  = (unsigned short*)(ws + 17310720);
  unsigned short* VTb  = (unsigned short*)(ws + 42476544);
  unsigned short* AO   = Xbf;

  cast_all<<<2313, 256, 0, stream>>>(Wq, Wk, Wv, Wo, bq, bk, bv,
                                     Wcat, Wobf, bcat);

  gemm1_bt<<<768, 256, 0, stream>>>(x, Wcat, bcat, QKb, VTb);

  attn_kernel<<<768, 256, 0, stream>>>(QKb, VTb, bias, AO);

  gemm2_bt<<<768, 256, 0, stream>>>(AO, Wobf, bo, out);
}

// Round 15
// 104.998 us; speedup vs baseline: 1.0169x; 1.0169x over previous
//
#include <hip/hip_runtime.h>

#define FEATS 768
#define NHEAD 12
#define HD    64
#define SEQ   1024
#define NB    8
#define MROWS (NB*SEQ)      // 8192
#define NQK   (2*FEATS)     // 1536
#define QKVN  (3*FEATS)     // 2304
#define QSC   0.0520616136f // (1/sqrt(768)) * log2(e), folded into Q at GEMM1 epilogue

typedef __attribute__((ext_vector_type(8))) __bf16          bf16x8;
typedef __attribute__((ext_vector_type(4))) __bf16          bf16x4;
typedef __attribute__((ext_vector_type(4))) unsigned short  us4;
typedef __attribute__((ext_vector_type(4))) float           f32x4;

__device__ __forceinline__ unsigned short f2bf(float f) {
  union { float f; unsigned u; } v; v.f = f;
  return (unsigned short)((v.u + 0x7fffu + ((v.u >> 16) & 1u)) >> 16);  // RNE
}

__device__ __forceinline__ void gload_lds16(const void* g, void* l) {
  __builtin_amdgcn_global_load_lds(
      (const __attribute__((address_space(1))) void*)g,
      (__attribute__((address_space(3))) void*)l, 16, 0, 0);
}

// ---------------- weight/bias casts (x-cast fused into gemm1) ----------------
__global__ void cast_all(const float* __restrict__ Wq, const float* __restrict__ Wk,
                         const float* __restrict__ Wv, const float* __restrict__ Wo,
                         const float* __restrict__ bq, const float* __restrict__ bk,
                         const float* __restrict__ bv,
                         unsigned short* __restrict__ Wcat,
                         unsigned short* __restrict__ Wobf,
                         float* __restrict__ bcat) {
  int blk = blockIdx.x;
  if (blk < 2304) {
    int mtx = blk / 576;
    int i = (blk % 576) * 256 + threadIdx.x;
    const float* src = (mtx == 0) ? Wq : (mtx == 1) ? Wk : (mtx == 2) ? Wv : Wo;
    f32x4 v = ((const f32x4*)src)[i];
    us4 o;
    o[0] = f2bf(v[0]); o[1] = f2bf(v[1]); o[2] = f2bf(v[2]); o[3] = f2bf(v[3]);
    if (mtx < 3) ((us4*)Wcat)[mtx * 147456 + i] = o;
    else         ((us4*)Wobf)[i] = o;
  } else {
    int i = (blk - 2304) * 256 + threadIdx.x;
    if (i < QKVN)
      bcat[i] = (i < FEATS) ? bq[i] : (i < 2*FEATS ? bk[i-FEATS] : bv[i-2*FEATS]);
  }
}

// read-side LDS swizzle (R7-R10 measured: 0 bank conflicts)
#define FOFF(row) ((row)*64 + (((g) ^ (((row) >> 1) & 3)) << 4))

// ---------------- GEMM1 v4: 128x192 tile, fused x-cast (f32 A reg-staged) ----------
// QKV = f2bf(x) * Wcat^T + bcat. ni 0..3 -> Q (pre-scaled by QSC), 4..7 -> K,
// 8..11 -> V^T (key columns PERMUTED per c(r) bit-perm -- see attn_kernel).
// A is staged from f32 x: issue 4 f32x4 loads of A(t+1) at top of iter t, convert
// (same RNE f2bf as the old cast pass) + 2x ds_write_b128 AFTER compute(t).
// (R14's top-hoisted WRITE_A regressed: its reg-wait drains to vmcnt(3) BEFORE
// this iter's prefetches are issued. Tail placement is the better of the two.)
__global__ __launch_bounds__(256, 3) void gemm1_bt(
    const float* __restrict__ X,
    const unsigned short* __restrict__ B,
    const float* __restrict__ bias,
    unsigned short* __restrict__ QKo,
    unsigned short* __restrict__ VTo)
{
  __shared__ __align__(16) char Al[2 * 8192];    // [buf][128 rows][64B] bf16
  __shared__ __align__(16) char Bl[3 * 12288];   // [buf][192 rows][64B]

  const int tid  = threadIdx.x;
  const int lane = tid & 63;
  const int w    = tid >> 6;
  const int l15  = lane & 15;
  const int g    = lane >> 4;
  const int wm   = (w >> 1) * 64;
  const int wn   = (w & 1) * 96;

  const int id  = blockIdx.x;            // 768 = 8 xcd * (8 mi * 12 ni)
  const int xcd = id & 7;
  const int j   = id >> 3;
  const int mi  = xcd * 8 + (j & 7);
  const int ni  = j >> 3;                // 0..11
  const int mbase = mi * 128;
  const int nbase = ni * 192;

  const int trow  = tid >> 2;
  const int sslot = ((tid & 3) ^ ((tid >> 3) & 3)) * 8;
  const float*          Ag = X + (size_t)(mbase + trow) * 768 + sslot;
  const unsigned short* Bg = B + (size_t)(nbase + trow) * 768 + sslot;

  f32x4 ar[4];   // A(t+1) in flight: rows {trow, trow+64}, elems sslot..+7 (f32)

  auto LOAD_A = [&](int t) {
    const float* sa = Ag + t * 32;
    ar[0] = *(const f32x4*)(sa);
    ar[1] = *(const f32x4*)(sa + 4);
    ar[2] = *(const f32x4*)(sa + 64*768);
    ar[3] = *(const f32x4*)(sa + 64*768 + 4);
  };
  auto WRITE_A = [&](int buf) {
    char* da = Al + buf * 8192 + tid * 16;
    us4 o0, o1;
#pragma unroll
    for (int k = 0; k < 4; k++) { o0[k] = f2bf(ar[0][k]); }
#pragma unroll
    for (int k = 0; k < 4; k++) { o1[k] = f2bf(ar[1][k]); }
    *(us4*)(da)     = o0;
    *(us4*)(da + 8) = o1;
#pragma unroll
    for (int k = 0; k < 4; k++) { o0[k] = f2bf(ar[2][k]); }
#pragma unroll
    for (int k = 0; k < 4; k++) { o1[k] = f2bf(ar[3][k]); }
    *(us4*)(da + 4096)     = o0;
    *(us4*)(da + 4096 + 8) = o1;
  };
  auto STAGE_B = [&](int buf, int t) {
    const unsigned short* sb = Bg + t * 32;
    char* db = Bl + buf * 12288 + tid * 16;
    gload_lds16(sb,            db);
    gload_lds16(sb + 64*768,   db + 4096);
    gload_lds16(sb + 128*768,  db + 8192);
  };

  f32x4 acc[4][6] = {};

  // prologue: A(0) regs, B(0), B(1); WRITE_A(0) waits A-regs; vmcnt(3) -> B(0)
  // landed, B(1) rides; lgkm drain; barrier.
  LOAD_A(0);
  STAGE_B(0, 0);
  STAGE_B(1, 1);
  WRITE_A(0);
  asm volatile("s_waitcnt vmcnt(3)" ::: "memory");
  asm volatile("s_waitcnt lgkmcnt(0)" ::: "memory");
  __builtin_amdgcn_s_barrier();

  for (int t = 0; t < 24; t++) {
    if (t < 23) LOAD_A(t + 1);
    if (t < 22) STAGE_B((t + 2) % 3, t + 2);

    const char* Ab = Al + (t & 1) * 8192;
    const char* Bb = Bl + (t % 3) * 12288;
    bf16x8 af[4];
#pragma unroll
    for (int mf = 0; mf < 4; mf++) {
      const int row = wm + mf*16 + l15;
      af[mf] = *(const bf16x8*)(Ab + FOFF(row));
    }
    __builtin_amdgcn_s_setprio(1);
#pragma unroll
    for (int nf = 0; nf < 6; nf++) {
      const int row = wn + nf*16 + l15;
      bf16x8 bfv = *(const bf16x8*)(Bb + FOFF(row));
#pragma unroll
      for (int mf = 0; mf < 4; mf++)
        acc[mf][nf] = __builtin_amdgcn_mfma_f32_16x16x32_bf16(af[mf], bfv, acc[mf][nf], 0, 0, 0);
    }
    __builtin_amdgcn_s_setprio(0);

    if (t < 23) {
      // WRITE_A's reg-wait drains all older VM ops incl. B(t+1); B(t+2)[3] rides.
      WRITE_A((t + 1) & 1);
      asm volatile("s_waitcnt vmcnt(3)" ::: "memory");   // no-op in steady state
      asm volatile("s_waitcnt lgkmcnt(0)" ::: "memory"); // ds_writes visible
      __builtin_amdgcn_s_barrier();
    }
  }

  // epilogue: D layout col = lane&15, row = (lane>>4)*4 + reg (m89-verified)
  const bool isQK = (ni < 8);            // block-uniform
  const float osc = (ni < 4) ? QSC : 1.0f;   // Q pre-scale (block-uniform)
#pragma unroll
  for (int mf = 0; mf < 4; mf++)
#pragma unroll
    for (int nf = 0; nf < 6; nf++) {
      const int col  = nbase + wn + nf*16 + l15;
      const float bb = bias[col];
      const int row0 = mbase + wm + mf*16 + g*4;
      if (isQK) {
#pragma unroll
        for (int r = 0; r < 4; r++)
          QKo[(size_t)(row0 + r)*NQK + col] = f2bf((acc[mf][nf][r] + bb) * osc);
      } else {
        const int c  = col - NQK;
        const int hh = c >> 6, dd = c & 63;
        const int bI = row0 >> 10, n0 = row0 & 1023;
        // key-column bit-permutation within the 64-key tile:
        // r = [b5b4 | b3b2 | b1b0] -> c = [b5 | b3b2 | b4 | b1b0]  (rr bits are 0)
        const int rl  = n0 & 63;
        const int cp  = ((rl >> 5) << 5) | (((rl >> 2) & 3) << 3) | (((rl >> 4) & 1) << 2);
        const int n0p = (n0 & ~63) | cp;
        us4 o;
#pragma unroll
        for (int r = 0; r < 4; r++) o[r] = f2bf(acc[mf][nf][r] + bb);
        *(us4*)(VTo + ((size_t)((bI*NHEAD + hh)*HD + dd))*SEQ + n0p) = o;
      }
    }
}

// ---------------- GEMM2: 64x128 tile, 768 blocks, asym A2/B3 counted-vmcnt ---------
// (R5-verified. FROZEN.)
__global__ __launch_bounds__(256, 4) void gemm2_bt(
    const unsigned short* __restrict__ A,
    const unsigned short* __restrict__ B,
    const float* __restrict__ bias,
    float* __restrict__ C)
{
  __shared__ __align__(16) char Al[2 * 4096];
  __shared__ __align__(16) char Bl[3 * 8192];

  const int tid  = threadIdx.x;
  const int lane = tid & 63;
  const int w    = tid >> 6;
  const int l15  = lane & 15;
  const int g    = lane >> 4;
  const int wm   = (w >> 1) * 32;
  const int wn   = (w & 1) * 64;

  const int id  = blockIdx.x;
  const int xcd = id & 7;
  const int j   = id >> 3;
  const int mi  = xcd * 16 + (j & 15);
  const int ni  = j >> 4;
  const int mbase = mi * 64;
  const int nbase = ni * 128;

  const int trow  = tid >> 2;
  const int sslot = ((tid & 3) ^ ((tid >> 3) & 3)) * 8;
  const unsigned short* Ag = A + (size_t)(mbase + trow) * 768 + sslot;
  const unsigned short* Bg = B + (size_t)(nbase + trow) * 768 + sslot;

  auto STAGE_A = [&](int buf, int t) {
    char* da = Al + buf * 4096 + tid * 16;
    gload_lds16(Ag + t * 32, da);
  };
  auto STAGE_B = [&](int buf, int t) {
    const unsigned short* sb = Bg + t * 32;
    char* db = Bl + buf * 8192 + tid * 16;
    gload_lds16(sb,           db);
    gload_lds16(sb + 64*768,  db + 4096);
  };

  f32x4 acc[2][4] = {};

  STAGE_A(0, 0);
  STAGE_B(0, 0);
  STAGE_B(1, 1);
  asm volatile("s_waitcnt vmcnt(2)" ::: "memory");   // A(0)+B(0) landed; B(1) in flight
  __builtin_amdgcn_s_barrier();

  for (int t = 0; t < 24; t++) {
    if (t < 23) STAGE_A((t + 1) & 1, t + 1);
    if (t < 22) STAGE_B((t + 2) % 3, t + 2);

    const char* Ab = Al + (t & 1) * 4096;
    const char* Bb = Bl + (t % 3) * 8192;
    bf16x8 af[2], bfv[4];
#pragma unroll
    for (int mf = 0; mf < 2; mf++) {
      const int row = wm + mf*16 + l15;
      af[mf] = *(const bf16x8*)(Ab + FOFF(row));
    }
#pragma unroll
    for (int nf = 0; nf < 4; nf++) {
      const int row = wn + nf*16 + l15;
      bfv[nf] = *(const bf16x8*)(Bb + FOFF(row));
    }
    __builtin_amdgcn_s_setprio(1);
#pragma unroll
    for (int mf = 0; mf < 2; mf++)
#pragma unroll
      for (int nf = 0; nf < 4; nf++)
        acc[mf][nf] = __builtin_amdgcn_mfma_f32_16x16x32_bf16(af[mf], bfv[nf], acc[mf][nf], 0, 0, 0);
    __builtin_amdgcn_s_setprio(0);

    if (t < 23) {
      if (t < 22) asm volatile("s_waitcnt vmcnt(2)" ::: "memory");
      else        asm volatile("s_waitcnt vmcnt(0)" ::: "memory");
      __builtin_amdgcn_s_barrier();
    }
  }

#pragma unroll
  for (int mf = 0; mf < 2; mf++)
#pragma unroll
    for (int nf = 0; nf < 4; nf++) {
      const int col  = nbase + wn + nf*16 + l15;
      const float bb = bias[col];
      const int row0 = mbase + wm + mf*16 + g*4;
#pragma unroll
      for (int r = 0; r < 4; r++)
        C[(size_t)(row0 + r)*FEATS + col] = acc[mf][nf][r] + bb;
    }
}
#undef FOFF

// ---------------- fused sigmoid attention v8 (R5-verified. FROZEN.) ----------------
// Pipeline QK(t) || sigmoid+PV(t-1); V staged one tile behind K; permuted-V
// in-register S (zero cross-lane: V^T key columns pre-permuted at GEMM1).
__global__ __launch_bounds__(256, 3) void attn_kernel(
    const unsigned short* __restrict__ QK,    // [8192][1536] (Q cols pre-scaled)
    const unsigned short* __restrict__ VT,    // [(b*12+h)*64 + d][1024], key-permuted
    const float* __restrict__ biasp,
    unsigned short* __restrict__ AO)          // [8192][768] bf16
{
  __shared__ __align__(16) char Kl[2][8192];   // [64 key][64 hd] bf16, XOR-swizzled
  __shared__ __align__(16) char Vl[2][8192];   // [64 d][64 keycol] bf16, XOR-swizzled

  const int tid  = threadIdx.x;
  const int lane = tid & 63;
  const int w    = tid >> 6;       // 0..3
  const int l15  = lane & 15;
  const int g    = lane >> 4;

  const int id  = blockIdx.x;
  const int r8  = id & 7;
  const int m   = id >> 3;
  const int bh  = r8 * 12 + (m >> 3);
  const int qx  = m & 7;
  const int b   = bh / NHEAD;
  const int h   = bh % NHEAD;
  const int rowB  = b * SEQ;
  const int qbase = rowB + qx * 128;

  const float Kb = __builtin_amdgcn_exp2f(-biasp[0] * 1.4426950408889634f);

  // Q fragments: qf[qm][ks], wave w rows [qbase+w*32+qm*16, +16)
  bf16x8 qf[2][2];
  {
    const unsigned short* qp = QK + (size_t)(qbase + w*32 + l15) * NQK + h*HD + g*8;
    qf[0][0] = *(const bf16x8*)(qp);
    qf[0][1] = *(const bf16x8*)(qp + 32);
    qf[1][0] = *(const bf16x8*)(qp + 16*NQK);
    qf[1][1] = *(const bf16x8*)(qp + 16*NQK + 32);
  }

  // staging: 256 thr x 16B = 4KB/issue; 2 issues per K tile (rows 0-31, 32-63), 2 per V
  const int trow = tid >> 3;                               // 0..31
  const int colb = ((tid & 7) * 16) ^ ((trow & 7) << 4);   // pre-swizzled source
  const char* Ksrc = (const char*)QK +
      ((size_t)(rowB + trow) * NQK + FEATS + h*HD) * 2 + colb;
  const char* Vsrc = (const char*)VT +
      ((size_t)(bh*HD + trow)) * (SEQ*2) + colb;

  auto STAGE_K = [&](int p, int t) {
    char* kw = Kl[p] + tid*16;
    gload_lds16(Ksrc + (size_t)t * 64 * (NQK*2),              kw);
    gload_lds16(Ksrc + (size_t)t * 64 * (NQK*2) + 32*(NQK*2), kw + 4096);
  };
  auto STAGE_V = [&](int p, int t) {
    char* vw = Vl[p] + tid*16;
    gload_lds16(Vsrc + t * 128,              vw);
    gload_lds16(Vsrc + t * 128 + 32*(SEQ*2), vw + 4096);
  };

  f32x4 o_acc[4][2] = {};
  f32x4 sE[2][4], sO[2][4];    // ping-pong score tiles (even/odd t)

  // sigmoid(prev scores) -> in-register bf16 B-frags (no cross-lane; V pre-permuted)
  auto SIGPV = [&](f32x4 (&sP)[2][4], const char* Vp) {
    bf16x8 paq[2][2];
#pragma unroll
    for (int qm = 0; qm < 2; qm++) {
      float sg[4][4];
#pragma unroll
      for (int nf = 0; nf < 4; nf++)
#pragma unroll
        for (int rr = 0; rr < 4; rr++) {
          const float e = __builtin_amdgcn_exp2f(-sP[qm][nf][rr]);
          sg[nf][rr] = __builtin_amdgcn_rcpf(__builtin_fmaf(Kb, e, 1.0f));
        }
#pragma unroll
      for (int js = 0; js < 2; js++) {
        bf16x8 pa;
#pragma unroll
        for (int jj = 0; jj < 4; jj++) {
          pa[jj]     = (__bf16)sg[2*js][jj];
          pa[jj + 4] = (__bf16)sg[2*js + 1][jj];
        }
        paq[qm][js] = pa;
      }
    }
#pragma unroll
    for (int js = 0; js < 2; js++) {
      bf16x8 vf[4];
#pragma unroll
      for (int df = 0; df < 4; df++) {
        const int row = df*16 + l15;
        const int by  = (row*128 + js*64 + g*16) ^ ((row & 7) << 4);
        vf[df] = *(const bf16x8*)(Vp + by);
      }
      __builtin_amdgcn_s_setprio(1);
#pragma unroll
      for (int df = 0; df < 4; df++)
#pragma unroll
        for (int qm = 0; qm < 2; qm++)
          o_acc[df][qm] = __builtin_amdgcn_mfma_f32_16x16x32_bf16(vf[df], paq[qm][js], o_acc[df][qm], 0, 0, 0);
      __builtin_amdgcn_s_setprio(0);
    }
  };

  // one pipeline stage: stage K(t+1),V(t); QK(t)->sC; sigmoid+PV of tile t-1; barrier
  auto BODY = [&](int t, f32x4 (&sC)[2][4], f32x4 (&sP)[2][4], bool stK, bool doPrev) {
    if (stK) STAGE_K((t + 1) & 1, t + 1);
    STAGE_V(t & 1, t);

    const char* Kp = Kl[t & 1];
#pragma unroll
    for (int qm = 0; qm < 2; qm++)
#pragma unroll
      for (int nf = 0; nf < 4; nf++)
        sC[qm][nf] = (f32x4){0.f, 0.f, 0.f, 0.f};
    __builtin_amdgcn_s_setprio(1);
#pragma unroll
    for (int nf = 0; nf < 4; nf++)
#pragma unroll
      for (int ks = 0; ks < 2; ks++) {
        const int row = nf*16 + l15;
        const int by  = (row*128 + ks*64 + g*16) ^ ((row & 7) << 4);
        bf16x8 kf = *(const bf16x8*)(Kp + by);
        sC[0][nf] = __builtin_amdgcn_mfma_f32_16x16x32_bf16(kf, qf[0][ks], sC[0][nf], 0, 0, 0);
        sC[1][nf] = __builtin_amdgcn_mfma_f32_16x16x32_bf16(kf, qf[1][ks], sC[1][nf], 0, 0, 0);
      }
    __builtin_amdgcn_s_setprio(0);

    if (doPrev) SIGPV(sP, Vl[(t - 1) & 1]);

    __syncthreads();
  };

  STAGE_K(0, 0);
  __syncthreads();

  BODY(0, sE, sO, true, false);          // QK(0); stage K(1),V(0)
#pragma unroll 1
  for (int t = 1; t < 15; t += 2) {
    BODY(t,     sO, sE, true, true);     // QK(t)  || sigmoid+PV(t-1)
    BODY(t + 1, sE, sO, true, true);
  }
  BODY(15, sO, sE, false, true);         // QK(15) || sigmoid+PV(14); stage V(15)
  SIGPV(sO, Vl[1]);                      // drain: sigmoid+PV(15)

  // ---- epilogue: o_acc[df][qm]: col=l15 -> q, row=df*16+g*4+rr -> d ----
  unsigned short* aop = AO + (size_t)(qbase + w*32) * FEATS + h*HD;
#pragma unroll
  for (int df = 0; df < 4; df++)
#pragma unroll
    for (int qm = 0; qm < 2; qm++) {
      const int q  = qm*16 + l15;
      const int d0 = df*16 + g*4;
      bf16x4 o;
#pragma unroll
      for (int rr = 0; rr < 4; rr++) o[rr] = (__bf16)o_acc[df][qm][rr];
      *(bf16x4*)(aop + (size_t)q * FEATS + d0) = o;
    }
}

// ---------------- launch ----------------
extern "C" void kernel_launch(void* const* d_in, const int* in_sizes, int n_in,
                              void* d_out, int out_size, void* d_ws, size_t ws_size,
                              hipStream_t stream) {
  const float* x    = (const float*)d_in[0];
  const float* bias = (const float*)d_in[1];
  const float* Wq   = (const float*)d_in[2];
  const float* bq   = (const float*)d_in[3];
  const float* Wk   = (const float*)d_in[4];
  const float* bk   = (const float*)d_in[5];
  const float* Wv   = (const float*)d_in[6];
  const float* bv   = (const float*)d_in[7];
  const float* Wo   = (const float*)d_in[8];
  const float* bo   = (const float*)d_in[9];
  float* out = (float*)d_out;

  char* ws = (char*)d_ws;
  unsigned short* Xbf  = (unsigned short*)(ws + 0);   // region reused as AO only
  unsigned short* Wcat = (unsigned short*)(ws + 12582912);
  unsigned short* Wobf = (unsigned short*)(ws + 16121856);
  float*          bcat = (float*)        (ws + 17301504);
  unsigned short* QKb  = (unsigned short*)(ws + 17310720);
  unsigned short* VTb  = (unsigned short*)(ws + 42476544);
  unsigned short* AO   = Xbf;

  cast_all<<<2313, 256, 0, stream>>>(Wq, Wk, Wv, Wo, bq, bk, bv,
                                     Wcat, Wobf, bcat);

  gemm1_bt<<<768, 256, 0, stream>>>(x, Wcat, bcat, QKb, VTb);

  attn_kernel<<<768, 256, 0, stream>>>(QKb, VTb, bias, AO);

  gemm2_bt<<<768, 256, 0, stream>>>(AO, Wobf, bo, out);
}